// Round 20
// baseline (218.473 us; speedup 1.0000x reference)
//
#include <hip/hip_runtime.h>
#include <hip/hip_bf16.h>

typedef __hip_bfloat16 bf16;
typedef __attribute__((ext_vector_type(8))) short bf16x8;
typedef __attribute__((ext_vector_type(4))) float f32x4;

#define NNODE 512   // B*N

__device__ __forceinline__ float b2f(bf16 v){ return __bfloat162float(v); }
__device__ __forceinline__ float siluf(float x){ return x / (1.f + __expf(-x)); }
__device__ __forceinline__ float tanhfast(float x){ return 1.f - 2.f/(__expf(2.f*x)+1.f); }
__device__ __forceinline__ float celu2(float x){ return x > 0.f ? x : 2.f*(__expf(0.5f*x)-1.f); }
__device__ __forceinline__ float bs2f(short v){ union{unsigned int i; float f;} t; t.i = ((unsigned int)(unsigned short)v) << 16; return t.f; }
__device__ __forceinline__ short f2bs(float x){ union{ bf16 b; short s; } u; u.b = __float2bfloat16(x); return u.s; }
__device__ __forceinline__ float lo16f(unsigned int u){ union{unsigned int i; float f;} t; t.i = u<<16; return t.f; }
__device__ __forceinline__ float hi16f(unsigned int u){ union{unsigned int i; float f;} t; t.i = u & 0xffff0000u; return t.f; }

// ---- dtype-polymorphic scalar load/store -------------------------------------------
template<typename T> __device__ __forceinline__ float ldv(const void* p, int i);
template<> __device__ __forceinline__ float ldv<float>(const void* p, int i){ return ((const float*)p)[i]; }
template<> __device__ __forceinline__ float ldv<bf16 >(const void* p, int i){ return b2f(((const bf16*)p)[i]); }

template<typename T> __device__ __forceinline__ void stv(void* p, int i, float v);
template<> __device__ __forceinline__ void stv<float>(void* p, int i, float v){ ((float*)p)[i] = v; }
template<> __device__ __forceinline__ void stv<bf16 >(void* p, int i, float v){ ((bf16*)p)[i] = __float2bfloat16(v); }

// load one element as bf16 bit-pattern (short)
template<typename T> __device__ __forceinline__ short ldbs(const void* p, int i);
template<> __device__ __forceinline__ short ldbs<bf16 >(const void* p, int i){ union{ bf16 b; short s; } u; u.b = ((const bf16*)p)[i]; return u.s; }
template<> __device__ __forceinline__ short ldbs<float>(const void* p, int i){ return f2bs(((const float*)p)[i]); }

struct Args {
    const void *h,*x,*v,*Win,*bin,*means,*betas,*Wo1,*bo1,*Wo2,*bo2,*Wsem,*bsem,*Wx,
               *Wp1,*bp1,*Wp2,*bp2,*Wn1,*bn1,*Wn2,*bn2,*Wv1,*bv1,*Wv2,*Wvm;
};

// ---- dtype detector: rbf_means[0] ~ 0.0067; read as bf16 low-half of an f32 it is huge
__global__ void k_detect(const void* means, int* flag){
    if (threadIdx.x == 0){
        float v = b2f(((const bf16*)means)[0]);
        flag[0] = (fabsf(v) > 1.0f || v != v) ? 1 : 0;   // 1 => inputs are float32
    }
}

// ---- per-node precompute: U1[j] (bf16) = h_j @ Wo1[0:64], Aj[j] = h_j @ Win[0:64] --
// Also transposes Wx -> WxT[n][k] (bf16).
template<typename T, int WANT>
__global__ void __launch_bounds__(64) k_nodepre(Args A, const int* __restrict__ flag,
                                                short* __restrict__ U1, float* __restrict__ Aj,
                                                short* __restrict__ WxT)
{
    if (flag[0] != WANT) return;
    int bn = blockIdx.x, t = threadIdx.x;
    __shared__ float sh[64];
    sh[t] = ldv<T>(A.h, bn*64 + t);
    __syncthreads();
    float u1 = 0.f;
    for (int f = 0; f < 64; ++f) u1 += sh[f] * ldv<T>(A.Wo1, f*64 + t);
    U1[bn*64 + t] = f2bs(u1);
    if (t < 50){
        float a1 = 0.f;
        for (int f = 0; f < 64; ++f) a1 += sh[f] * ldv<T>(A.Win, f*50 + t);
        Aj[bn*64 + t] = a1;
    }
    // transpose Wx: 2 elements per thread
    int e = (bn*64 + t)*2;        // 0..65534
    int k = e >> 8, n = e & 255;
    WxT[n*256 + k]     = ldbs<T>(A.Wx, k*256 + n);
    WxT[(n+1)*256 + k] = ldbs<T>(A.Wx, k*256 + n + 1);
}

// ---- fused SAKE layer: one block per (b,i) node; 256 threads (4 waves) -------------
// R19 base (218us, 2 blocks/CU) + mixing register diet: the wave's 64 c-columns are
// processed as TWO sequential 32-column halves (Cc[4][2]=32 AGPR, Bf[2]) so the live
// set fits the (256,2) cap WITHOUT the ~40MB/dispatch spill traffic R19 showed
// (FETCH 16MB / WRITE 27MB -> expect ~3MB / ~0.2MB).
template<typename T, int WANT>
__global__ void __launch_bounds__(256, 2) k_sake(Args A, const int* __restrict__ flag,
                                                 const short* __restrict__ U1w,
                                                 const float* __restrict__ Ajw,
                                                 const short* __restrict__ wxt,
                                                 void* __restrict__ out)
{
    if (flag[0] != WANT) return;

    int bi = blockIdx.x;
    int b = bi >> 8, i = bi & 255;
    int tid = threadIdx.x, w = tid >> 6, lane = tid & 63;

    __shared__ float s_hi[64];           // h_i                          256 B
    __shared__ bf16  s_e[256][66];       // edge features (row padded)  33.8 KB
    __shared__ float s_att[256][4];      // logits -> softmax weights      4 KB
    __shared__ float s_x4[256][4];       // xhat[3], d                     4 KB
    __shared__ __align__(16) float s_rbfh[4][4][68]; // per-wave, k-pad  4.25 KB
    __shared__ __align__(16) float s_mid[4][4][68];  // per-wave scratch 4.25 KB
    __shared__ float s_sm[1024];         // softmax scratch                4 KB
    __shared__ float s_red[768];         // comb_sum result                3 KB
    __shared__ float s_he[256];          // h_e                            1 KB
    __shared__ float s_cn[256];          // comb_norm                      1 KB
    __shared__ float s_f1[64], s_f2[64], s_f3[64], s_f4[64];  //           1 KB
    __shared__ __align__(16) short s_wo2t[64*72];   // Wo2^T [n][k+8]     9 KB
    __shared__ __align__(16) short s_wo1t[64*72];   // Wo1r^T [n][k+8]    9 KB
    __shared__ short s_wsem[256];        // Wsem staged bf16             512 B
    __shared__ float s_u2[64], s_bo1[64], s_wl[64]; // o1 C-init consts  768 B

    s_red[tid] = 0.f; s_red[tid+256] = 0.f; s_red[tid+512] = 0.f;
    if (tid < 64) s_hi[tid] = ldv<T>(A.h, bi*64 + tid);
    s_wsem[tid] = ldbs<T>(A.Wsem, tid);
    // stage Wo2^T and Wo1r^T into LDS ([n][k] with k-pad 8; rows k>=50 of Wo1r zero)
    #pragma unroll
    for (int q = 0; q < 16; ++q){
        int idx = q*256 + tid;           // 0..4095
        int n = idx >> 6, k = idx & 63;
        s_wo2t[n*72 + k] = ldbs<T>(A.Wo2, k*64 + n);
        s_wo1t[n*72 + k] = (k < 50) ? ldbs<T>(A.Wo1, (128+k)*64 + n) : (short)0;
    }
    // zero-pad rbfh k-range [50,68) once (each pass only rewrites k<50)
    {
        int k = lane;
        if (k >= 50){
            #pragma unroll
            for (int pp = 0; pp < 4; ++pp){ s_rbfh[w][pp][k] = 0.f; s_rbfh[w][pp][k+4 < 68 ? k+4 : 67] = 0.f; }
        }
    }

    float xi0 = ldv<T>(A.x, bi*3+0), xi1 = ldv<T>(A.x, bi*3+1), xi2 = ldv<T>(A.x, bi*3+2);

    // ---- s_x4 precompute: thread j computes xhat + d once ----
    {
        int j = tid;
        float dx = ldv<T>(A.x,(b*256+j)*3+0) - xi0;
        float dy = ldv<T>(A.x,(b*256+j)*3+1) - xi1;
        float dz = ldv<T>(A.x,(b*256+j)*3+2) - xi2;
        float dd = sqrtf(dx*dx + dy*dy + dz*dz + 1e-5f);
        float inv = 1.f/(dd + 1e-5f);
        s_x4[j][0] = dx*inv; s_x4[j][1] = dy*inv; s_x4[j][2] = dz*inv; s_x4[j][3] = dd;
    }

    int lane15 = lane & 15, quad = lane >> 4;

    // per-lane i-side constants
    float bo1v  = ldv<T>(A.bo1, lane);
    float wlast = ldv<T>(A.Wo1, 178*64 + lane);
    float u2v = 0.f;
    for (int f = 0; f < 64; ++f) u2v += s_hi[f] * ldv<T>(A.Wo1, (64+f)*64 + lane);
    if (w == 0){ s_u2[lane] = u2v; s_bo1[lane] = bo1v; s_wl[lane] = wlast; }
    float muv = 0.f, bev = 0.f, binv = 0.f, aiv = 0.f;
    if (lane < 50){
        muv = ldv<T>(A.means, lane); bev = ldv<T>(A.betas, lane); binv = ldv<T>(A.bin, lane);
        for (int f = 0; f < 64; ++f) aiv += s_hi[f] * ldv<T>(A.Win, (64+f)*50 + lane);
    }
    __syncthreads();   // all staged LDS + s_x4 + s_u2/s_bo1/s_wl visible

    float bo2c[4], u24[4], bo14[4], wl4[4];
    #pragma unroll
    for (int nf = 0; nf < 4; ++nf){
        bo2c[nf] = ldv<T>(A.bo2, nf*16 + lane15);
        u24[nf]  = s_u2[nf*16 + lane15];
        bo14[nf] = s_bo1[nf*16 + lane15];
        wl4[nf]  = s_wl[nf*16 + lane15];
    }

    // ================= edge phase: 16 passes x (4 waves x 4 pairs) =================
    for (int pass = 0; pass < 16; ++pass){
        int j0 = pass*16 + w*4;
        float dist[4];
        #pragma unroll
        for (int pp = 0; pp < 4; ++pp) dist[pp] = s_x4[j0+pp][3];

        if (lane < 50){
            #pragma unroll
            for (int pp = 0; pp < 4; ++pp){
                int j = j0 + pp;
                float h1 = Ajw[(b*256+j)*64 + lane] + aiv + binv;
                float dd = dist[pp];
                float cut = (dd < 5.f) ? 0.5f*(__cosf(dd*0.6283185307f) + 1.f) : 0.f;
                float ex = __expf(-dd) - muv;
                s_rbfh[w][pp][lane] = cut * __expf(-bev*ex*ex) * h1;
            }
        }

        // ---- o1 via MFMA: [4 pairs x 64k(rbfh, zero-pad)] @ Wo1r[64k x 64n] ----
        {
            bf16x8 ar[2];
            #pragma unroll
            for (int kk2 = 0; kk2 < 2; ++kk2){
                bf16x8 av = (bf16x8){0,0,0,0,0,0,0,0};
                if (lane15 < 4){
                    const float* rp = &s_rbfh[w][lane15][kk2*32 + quad*8];
                    f32x4 m0 = *(const f32x4*)rp;
                    f32x4 m1 = *(const f32x4*)(rp + 4);
                    av[0]=f2bs(m0[0]); av[1]=f2bs(m0[1]); av[2]=f2bs(m0[2]); av[3]=f2bs(m0[3]);
                    av[4]=f2bs(m1[0]); av[5]=f2bs(m1[1]); av[6]=f2bs(m1[2]); av[7]=f2bs(m1[3]);
                }
                ar[kk2] = av;
            }
            #pragma unroll
            for (int nf = 0; nf < 4; ++nf){
                int n = nf*16 + lane15;
                f32x4 Co1 = (f32x4){0.f,0.f,0.f,0.f};
                if (quad == 0){
                    #pragma unroll
                    for (int r = 0; r < 4; ++r)
                        Co1[r] = bs2f(U1w[(b*256 + j0 + r)*64 + n]) + u24[nf] + bo14[nf] + dist[r]*wl4[nf];
                }
                bf16x8 b0 = *(const bf16x8*)&s_wo1t[n*72 + quad*8];
                bf16x8 b1 = *(const bf16x8*)&s_wo1t[n*72 + 32 + quad*8];
                Co1 = __builtin_amdgcn_mfma_f32_16x16x32_bf16(ar[0], b0, Co1, 0, 0, 0);
                Co1 = __builtin_amdgcn_mfma_f32_16x16x32_bf16(ar[1], b1, Co1, 0, 0, 0);
                if (quad == 0){
                    s_mid[w][0][n] = siluf(Co1[0]);
                    s_mid[w][1][n] = siluf(Co1[1]);
                    s_mid[w][2][n] = siluf(Co1[2]);
                    s_mid[w][3][n] = siluf(Co1[3]);
                }
            }
        }

        // ---- o2 via MFMA: [4 pairs x 64k] @ Wo2[64k x 64n]; A rows 4..15 zero ----
        {
            bf16x8 av2[2];
            #pragma unroll
            for (int kk2 = 0; kk2 < 2; ++kk2){
                bf16x8 av = (bf16x8){0,0,0,0,0,0,0,0};
                if (lane15 < 4){
                    const float* mp = &s_mid[w][lane15][kk2*32 + quad*8];
                    f32x4 m0 = *(const f32x4*)mp;
                    f32x4 m1 = *(const f32x4*)(mp + 4);
                    av[0]=f2bs(m0[0]); av[1]=f2bs(m0[1]); av[2]=f2bs(m0[2]); av[3]=f2bs(m0[3]);
                    av[4]=f2bs(m1[0]); av[5]=f2bs(m1[1]); av[6]=f2bs(m1[2]); av[7]=f2bs(m1[3]);
                }
                av2[kk2] = av;
            }
            #pragma unroll
            for (int nf = 0; nf < 4; ++nf){
                int n = nf*16 + lane15;
                f32x4 Cc2 = (f32x4){bo2c[nf], bo2c[nf], bo2c[nf], bo2c[nf]};
                bf16x8 b0 = *(const bf16x8*)&s_wo2t[n*72 + quad*8];
                bf16x8 b1 = *(const bf16x8*)&s_wo2t[n*72 + 32 + quad*8];
                Cc2 = __builtin_amdgcn_mfma_f32_16x16x32_bf16(av2[0], b0, Cc2, 0, 0, 0);
                Cc2 = __builtin_amdgcn_mfma_f32_16x16x32_bf16(av2[1], b1, Cc2, 0, 0, 0);
                if (quad == 0){
                    s_e[j0+0][n] = __float2bfloat16(Cc2[0]);
                    s_e[j0+1][n] = __float2bfloat16(Cc2[1]);
                    s_e[j0+2][n] = __float2bfloat16(Cc2[2]);
                    s_e[j0+3][n] = __float2bfloat16(Cc2[3]);
                }
            }
        }
    }
    __syncthreads();   // single barrier: s_e now visible to all waves

    // ================= semantic attention logits (thread = j; b32 e-reads) =========
    {
        int j = tid;
        float a0 = ldv<T>(A.bsem,0), a1 = ldv<T>(A.bsem,1), a2 = ldv<T>(A.bsem,2), a3 = ldv<T>(A.bsem,3);
        const unsigned int* erow = (const unsigned int*)&s_e[j][0];   // j*33 dwords, aligned
        for (int f2 = 0; f2 < 32; ++f2){
            unsigned int u = erow[f2];
            float e0 = lo16f(u), e1 = hi16f(u);
            a0 += e0*bs2f(s_wsem[f2*8+0]) + e1*bs2f(s_wsem[f2*8+4]);
            a1 += e0*bs2f(s_wsem[f2*8+1]) + e1*bs2f(s_wsem[f2*8+5]);
            a2 += e0*bs2f(s_wsem[f2*8+2]) + e1*bs2f(s_wsem[f2*8+6]);
            a3 += e0*bs2f(s_wsem[f2*8+3]) + e1*bs2f(s_wsem[f2*8+7]);
        }
        a0 = celu2(a0); a1 = celu2(a1); a2 = celu2(a2); a3 = celu2(a3);
        if (j == i){ a0 -= 1e5f; a1 -= 1e5f; a2 -= 1e5f; a3 -= 1e5f; }
        s_att[j][0] = a0; s_att[j][1] = a1; s_att[j][2] = a2; s_att[j][3] = a3;
    }
    __syncthreads();

    // ================= softmax over j (4 heads) =================
    {
        float l0 = s_att[tid][0], l1 = s_att[tid][1], l2 = s_att[tid][2], l3 = s_att[tid][3];
        s_sm[tid*4+0]=l0; s_sm[tid*4+1]=l1; s_sm[tid*4+2]=l2; s_sm[tid*4+3]=l3;
        __syncthreads();
        for (int off = 128; off > 0; off >>= 1){
            if (tid < off){
                s_sm[tid*4+0] = fmaxf(s_sm[tid*4+0], s_sm[(tid+off)*4+0]);
                s_sm[tid*4+1] = fmaxf(s_sm[tid*4+1], s_sm[(tid+off)*4+1]);
                s_sm[tid*4+2] = fmaxf(s_sm[tid*4+2], s_sm[(tid+off)*4+2]);
                s_sm[tid*4+3] = fmaxf(s_sm[tid*4+3], s_sm[(tid+off)*4+3]);
            }
            __syncthreads();
        }
        float m0 = s_sm[0], m1 = s_sm[1], m2 = s_sm[2], m3 = s_sm[3];
        __syncthreads();
        float e0 = __expf(l0-m0), e1 = __expf(l1-m1), e2 = __expf(l2-m2), e3 = __expf(l3-m3);
        s_sm[tid*4+0]=e0; s_sm[tid*4+1]=e1; s_sm[tid*4+2]=e2; s_sm[tid*4+3]=e3;
        __syncthreads();
        for (int off = 128; off > 0; off >>= 1){
            if (tid < off){
                s_sm[tid*4+0] += s_sm[(tid+off)*4+0];
                s_sm[tid*4+1] += s_sm[(tid+off)*4+1];
                s_sm[tid*4+2] += s_sm[(tid+off)*4+2];
                s_sm[tid*4+3] += s_sm[(tid+off)*4+3];
            }
            __syncthreads();
        }
        s_att[tid][0] = e0 / s_sm[0];
        s_att[tid][1] = e1 / s_sm[1];
        s_att[tid][2] = e2 / s_sm[2];
        s_att[tid][3] = e3 / s_sm[3];
    }
    __syncthreads();

    // ================= h_e[c] = sum_j e[j][f]*att[j][h], c = 4f+h (R16 proven) ======
    {
        int f_he = tid >> 2, h_he = tid & 3;
        float he_acc = 0.f;
        for (int j2 = 0; j2 < 256; ++j2)
            he_acc += b2f(s_e[j2][f_he]) * s_att[j2][h_he];
        s_he[tid] = he_acc;
    }

    // ================= x-mixing via MFMA: P = A @ Wx, A[j,4f+h]=e[j][f]*att[j][h] ====
    // wave w owns c-slice [w*64, w*64+64), processed as TWO sequential 32-col halves
    {
        const short* se_s = (const short*)s_e;   // s_e[j][f] -> se_s[j*66+f]

        for (int chalf = 0; chalf < 2; ++chalf){
            int n0 = w*64 + chalf*32;
            float comb_acc[2][3];
            #pragma unroll
            for (int nf = 0; nf < 2; ++nf){ comb_acc[nf][0]=0.f; comb_acc[nf][1]=0.f; comb_acc[nf][2]=0.f; }

            for (int jt = 0; jt < 4; ++jt){
                int jbase = jt*64;
                f32x4 Cc[4][2];
                #pragma unroll
                for (int mf = 0; mf < 4; ++mf)
                    #pragma unroll
                    for (int nf = 0; nf < 2; ++nf)
                        Cc[mf][nf] = (f32x4){0.f, 0.f, 0.f, 0.f};

                float am[4][4];
                #pragma unroll
                for (int mf = 0; mf < 4; ++mf){
                    int jr = jbase + mf*16 + lane15;
                    am[mf][0] = s_att[jr][0]; am[mf][1] = s_att[jr][1];
                    am[mf][2] = s_att[jr][2]; am[mf][3] = s_att[jr][3];
                }

                for (int kk = 0; kk < 8; ++kk){
                    bf16x8 Bf[2];
                    #pragma unroll
                    for (int nf = 0; nf < 2; ++nf){
                        int n = n0 + nf*16 + lane15;
                        Bf[nf] = *(const bf16x8*)(wxt + n*256 + kk*32 + quad*8);
                    }
                    int f0 = kk*8 + quad*2;
                    bf16x8 Af[4];
                    #pragma unroll
                    for (int mf = 0; mf < 4; ++mf){
                        int jr = jbase + mf*16 + lane15;
                        float e0 = bs2f(se_s[jr*66 + f0]);
                        float e1 = bs2f(se_s[jr*66 + f0 + 1]);
                        bf16x8 av;
                        av[0]=f2bs(e0*am[mf][0]); av[1]=f2bs(e0*am[mf][1]);
                        av[2]=f2bs(e0*am[mf][2]); av[3]=f2bs(e0*am[mf][3]);
                        av[4]=f2bs(e1*am[mf][0]); av[5]=f2bs(e1*am[mf][1]);
                        av[6]=f2bs(e1*am[mf][2]); av[7]=f2bs(e1*am[mf][3]);
                        Af[mf] = av;
                    }
                    #pragma unroll
                    for (int mf = 0; mf < 4; ++mf)
                        #pragma unroll
                        for (int nf = 0; nf < 2; ++nf)
                            Cc[mf][nf] = __builtin_amdgcn_mfma_f32_16x16x32_bf16(Af[mf], Bf[nf], Cc[mf][nf], 0, 0, 0);
                }

                #pragma unroll
                for (int mf = 0; mf < 4; ++mf){
                    #pragma unroll
                    for (int r = 0; r < 4; ++r){
                        int j = jbase + mf*16 + quad*4 + r;
                        float x0 = s_x4[j][0], x1 = s_x4[j][1], x2 = s_x4[j][2];
                        #pragma unroll
                        for (int nf = 0; nf < 2; ++nf){
                            float cf = tanhfast(Cc[mf][nf][r]);
                            comb_acc[nf][0] += cf*x0;
                            comb_acc[nf][1] += cf*x1;
                            comb_acc[nf][2] += cf*x2;
                        }
                    }
                }
            }

            #pragma unroll
            for (int nf = 0; nf < 2; ++nf){
                #pragma unroll
                for (int d = 0; d < 3; ++d){
                    float vsum = comb_acc[nf][d];
                    vsum += __shfl_xor(vsum, 16);
                    vsum += __shfl_xor(vsum, 32);
                    if (quad == 0) s_red[(n0 + nf*16 + lane15)*3 + d] = vsum;
                }
            }
        }
    }
    __syncthreads();

    // ================= final per-node MLPs =================
    const float sc = 1.f/256.f;
    {
        float cb0 = s_red[tid*3+0]*sc, cb1 = s_red[tid*3+1]*sc, cb2 = s_red[tid*3+2]*sc;
        s_cn[tid] = cb0*cb0 + cb1*cb1 + cb2*cb2;
    }
    __syncthreads();

    if (tid < 64){
        int f = tid;
        float acc = ldv<T>(A.bp1, f);
        for (int c = 0; c < 256; ++c) acc += s_cn[c] * ldv<T>(A.Wp1, c*64 + f);
        s_f1[f] = siluf(acc);
    }
    __syncthreads();
    if (tid < 64){
        int f = tid;
        float acc = ldv<T>(A.bp2, f);
        for (int k = 0; k < 64; ++k) acc += s_f1[k] * ldv<T>(A.Wp2, k*64 + f);
        s_f2[f] = siluf(acc);
    }
    __syncthreads();
    if (tid < 64){
        int f = tid;
        float acc = ldv<T>(A.bn1, f);
        for (int r = 0; r < 64; ++r)  acc += s_hi[r] * ldv<T>(A.Wn1, r*64 + f);
        for (int r = 0; r < 256; ++r) acc += s_he[r] * ldv<T>(A.Wn1, (64+r)*64 + f);
        for (int r = 0; r < 64; ++r)  acc += s_f2[r] * ldv<T>(A.Wn1, (320+r)*64 + f);
        s_f3[f] = siluf(acc);
    }
    __syncthreads();
    if (tid < 64){
        int f = tid;
        float acc = ldv<T>(A.bn2, f);
        for (int k = 0; k < 64; ++k) acc += s_f3[k] * ldv<T>(A.Wn2, k*64 + f);
        float hn = s_hi[f] + siluf(acc);
        stv<T>(out, bi*64 + f, hn);
        s_f4[f] = hn;
    }
    __syncthreads();
    if (tid < 64){
        int f = tid;
        float acc = ldv<T>(A.bv1, f);
        for (int k = 0; k < 64; ++k) acc += s_f4[k] * ldv<T>(A.Wv1, k*64 + f);
        float term = siluf(acc) * ldv<T>(A.Wv2, f);
        #pragma unroll
        for (int off = 32; off > 0; off >>= 1) term += __shfl_down(term, off);
        float vscale = 2.f / (1.f + __expf(-__shfl(term, 0)));

        float dv0 = 0.f, dv1 = 0.f, dv2 = 0.f;
        #pragma unroll
        for (int q = 0; q < 4; ++q){
            int c = q*64 + f;
            float wv = ldv<T>(A.Wvm, c);
            dv0 += s_red[c*3+0]*sc*wv;
            dv1 += s_red[c*3+1]*sc*wv;
            dv2 += s_red[c*3+2]*sc*wv;
        }
        #pragma unroll
        for (int off = 32; off > 0; off >>= 1){
            dv0 += __shfl_down(dv0, off);
            dv1 += __shfl_down(dv1, off);
            dv2 += __shfl_down(dv2, off);
        }
        dv0 = __shfl(dv0, 0); dv1 = __shfl(dv1, 0); dv2 = __shfl(dv2, 0);
        if (f < 3){
            float dvl = (f == 0) ? dv0 : (f == 1 ? dv1 : dv2);
            float vn = dvl + vscale * ldv<T>(A.v, bi*3 + f);
            float xn = ldv<T>(A.x, bi*3 + f) + vn;
            stv<T>(out, 32768 + bi*3 + f, xn);  // x_new
            stv<T>(out, 34304 + bi*3 + f, vn);  // v_new
        }
    }
}

extern "C" void kernel_launch(void* const* d_in, const int* in_sizes, int n_in,
                              void* d_out, int out_size, void* d_ws, size_t ws_size,
                              hipStream_t stream)
{
    Args A;
    A.h     = d_in[0];  A.x     = d_in[1];  A.v     = d_in[2];
    A.Win   = d_in[3];  A.bin   = d_in[4];  A.means = d_in[5];  A.betas = d_in[6];
    A.Wo1   = d_in[7];  A.bo1   = d_in[8];  A.Wo2   = d_in[9];  A.bo2   = d_in[10];
    A.Wsem  = d_in[11]; A.bsem  = d_in[12]; A.Wx    = d_in[13];
    A.Wp1   = d_in[14]; A.bp1   = d_in[15]; A.Wp2   = d_in[16]; A.bp2   = d_in[17];
    A.Wn1   = d_in[18]; A.bn1   = d_in[19]; A.Wn2   = d_in[20]; A.bn2   = d_in[21];
    A.Wv1   = d_in[22]; A.bv1   = d_in[23]; A.Wv2   = d_in[24]; A.Wvm   = d_in[25];

    // ws layout: flag 64B | U1 bf16 512x64 (64KB) | Aj f32 512x64 (128KB) | WxT bf16 256x256 (128KB)
    int*   flag = (int*)d_ws;
    short* U1b  = (short*)((char*)d_ws + 64);
    float* Aj   = (float*)((char*)d_ws + 64 + 65536);
    short* WxT  = (short*)((char*)d_ws + 64 + 65536 + 131072);

    k_detect<<<1, 64, 0, stream>>>(A.means, flag);
    k_nodepre<bf16,  0><<<NNODE, 64, 0, stream>>>(A, flag, U1b, Aj, WxT);
    k_nodepre<float, 1><<<NNODE, 64, 0, stream>>>(A, flag, U1b, Aj, WxT);
    k_sake<bf16,  0><<<NNODE, 256, 0, stream>>>(A, flag, U1b, Aj, WxT, d_out);
    k_sake<float, 1><<<NNODE, 256, 0, stream>>>(A, flag, U1b, Aj, WxT, d_out);
}

// Round 21
// 216.241 us; speedup vs baseline: 1.0103x; 1.0103x over previous
//
#include <hip/hip_runtime.h>
#include <hip/hip_bf16.h>

typedef __hip_bfloat16 bf16;
typedef __attribute__((ext_vector_type(8))) short bf16x8;
typedef __attribute__((ext_vector_type(4))) float f32x4;

#define NNODE 512   // B*N

__device__ __forceinline__ float b2f(bf16 v){ return __bfloat162float(v); }
__device__ __forceinline__ float siluf(float x){ return x / (1.f + __expf(-x)); }
__device__ __forceinline__ float tanhfast(float x){ return 1.f - 2.f/(__expf(2.f*x)+1.f); }
__device__ __forceinline__ float celu2(float x){ return x > 0.f ? x : 2.f*(__expf(0.5f*x)-1.f); }
__device__ __forceinline__ float bs2f(short v){ union{unsigned int i; float f;} t; t.i = ((unsigned int)(unsigned short)v) << 16; return t.f; }
__device__ __forceinline__ short f2bs(float x){ union{ bf16 b; short s; } u; u.b = __float2bfloat16(x); return u.s; }
__device__ __forceinline__ float lo16f(unsigned int u){ union{unsigned int i; float f;} t; t.i = u<<16; return t.f; }
__device__ __forceinline__ float hi16f(unsigned int u){ union{unsigned int i; float f;} t; t.i = u & 0xffff0000u; return t.f; }

// ---- dtype-polymorphic scalar load/store -------------------------------------------
template<typename T> __device__ __forceinline__ float ldv(const void* p, int i);
template<> __device__ __forceinline__ float ldv<float>(const void* p, int i){ return ((const float*)p)[i]; }
template<> __device__ __forceinline__ float ldv<bf16 >(const void* p, int i){ return b2f(((const bf16*)p)[i]); }

template<typename T> __device__ __forceinline__ void stv(void* p, int i, float v);
template<> __device__ __forceinline__ void stv<float>(void* p, int i, float v){ ((float*)p)[i] = v; }
template<> __device__ __forceinline__ void stv<bf16 >(void* p, int i, float v){ ((bf16*)p)[i] = __float2bfloat16(v); }

// load one element as bf16 bit-pattern (short)
template<typename T> __device__ __forceinline__ short ldbs(const void* p, int i);
template<> __device__ __forceinline__ short ldbs<bf16 >(const void* p, int i){ union{ bf16 b; short s; } u; u.b = ((const bf16*)p)[i]; return u.s; }
template<> __device__ __forceinline__ short ldbs<float>(const void* p, int i){ return f2bs(((const float*)p)[i]); }

struct Args {
    const void *h,*x,*v,*Win,*bin,*means,*betas,*Wo1,*bo1,*Wo2,*bo2,*Wsem,*bsem,*Wx,
               *Wp1,*bp1,*Wp2,*bp2,*Wn1,*bn1,*Wn2,*bn2,*Wv1,*bv1,*Wv2,*Wvm;
};

// ---- dtype detector: rbf_means[0] ~ 0.0067; read as bf16 low-half of an f32 it is huge
__global__ void k_detect(const void* means, int* flag){
    if (threadIdx.x == 0){
        float v = b2f(((const bf16*)means)[0]);
        flag[0] = (fabsf(v) > 1.0f || v != v) ? 1 : 0;   // 1 => inputs are float32
    }
}

// ---- per-node precompute: U1[j] (bf16) = h_j @ Wo1[0:64], Aj[j] = h_j @ Win[0:64] --
// Also builds WxH[h][n][f] (bf16) = Wx[4f+h][n] with COALESCED writes (R14-R20's
// [n][k] transpose wrote at 1KB stride -> ~35us of scattered-write time).
template<typename T, int WANT>
__global__ void __launch_bounds__(64) k_nodepre(Args A, const int* __restrict__ flag,
                                                short* __restrict__ U1, float* __restrict__ Aj,
                                                short* __restrict__ WxT)
{
    if (flag[0] != WANT) return;
    int bn = blockIdx.x, t = threadIdx.x;
    __shared__ float sh[64];
    sh[t] = ldv<T>(A.h, bn*64 + t);
    __syncthreads();
    float u1 = 0.f;
    for (int f = 0; f < 64; ++f) u1 += sh[f] * ldv<T>(A.Wo1, f*64 + t);
    U1[bn*64 + t] = f2bs(u1);
    if (t < 50){
        float a1 = 0.f;
        for (int f = 0; f < 64; ++f) a1 += sh[f] * ldv<T>(A.Win, f*50 + t);
        Aj[bn*64 + t] = a1;
    }
    // WxH[h][n][f]: output index o consecutive per thread -> coalesced writes
    int o = (bn*64 + t)*2;
    #pragma unroll
    for (int q = 0; q < 2; ++q){
        int oo = o + q;
        int hh = oo >> 14, rem = oo & 16383, n = rem >> 6, f = rem & 63;
        WxT[oo] = ldbs<T>(A.Wx, (4*f + hh)*256 + n);
    }
}

// ---- fused SAKE layer: one block per (b,i) node; 256 threads (4 waves) -------------
// R20 base (218us) with the mixing GEMM restructured via the att-factorization:
//   P[j][n] = sum_h att[j][h] * (E @ WxH_h)[j][n]
// A-operand is s_e DIRECTLY (no per-element e*att build + bf16 repack -> the ~5k-VALU
// A-construction disappears). nf-outer loop hoists B (8 bf16x8) per nf: 32 global
// b128 B-loads per wave total. Same 512 MFMA/wave. (256,2) cap kept (no spills @R20).
template<typename T, int WANT>
__global__ void __launch_bounds__(256, 2) k_sake(Args A, const int* __restrict__ flag,
                                                 const short* __restrict__ U1w,
                                                 const float* __restrict__ Ajw,
                                                 const short* __restrict__ wxt,
                                                 void* __restrict__ out)
{
    if (flag[0] != WANT) return;

    int bi = blockIdx.x;
    int b = bi >> 8, i = bi & 255;
    int tid = threadIdx.x, w = tid >> 6, lane = tid & 63;

    __shared__ float s_hi[64];           // h_i                          256 B
    __shared__ bf16  s_e[256][66];       // edge features (row padded)  33.8 KB
    __shared__ float s_att[256][4];      // logits -> softmax weights      4 KB
    __shared__ float s_x4[256][4];       // xhat[3], d                     4 KB
    __shared__ __align__(16) float s_rbfh[4][4][68]; // per-wave, k-pad  4.25 KB
    __shared__ __align__(16) float s_mid[4][4][68];  // per-wave scratch 4.25 KB
    __shared__ float s_sm[1024];         // softmax scratch                4 KB
    __shared__ float s_red[768];         // comb_sum result                3 KB
    __shared__ float s_he[256];          // h_e                            1 KB
    __shared__ float s_cn[256];          // comb_norm                      1 KB
    __shared__ float s_f1[64], s_f2[64], s_f3[64], s_f4[64];  //           1 KB
    __shared__ __align__(16) short s_wo2t[64*72];   // Wo2^T [n][k+8]     9 KB
    __shared__ __align__(16) short s_wo1t[64*72];   // Wo1r^T [n][k+8]    9 KB
    __shared__ short s_wsem[256];        // Wsem staged bf16             512 B
    __shared__ float s_u2[64], s_bo1[64], s_wl[64]; // o1 C-init consts  768 B

    s_red[tid] = 0.f; s_red[tid+256] = 0.f; s_red[tid+512] = 0.f;
    if (tid < 64) s_hi[tid] = ldv<T>(A.h, bi*64 + tid);
    s_wsem[tid] = ldbs<T>(A.Wsem, tid);
    // stage Wo2^T and Wo1r^T into LDS ([n][k] with k-pad 8; rows k>=50 of Wo1r zero)
    #pragma unroll
    for (int q = 0; q < 16; ++q){
        int idx = q*256 + tid;           // 0..4095
        int n = idx >> 6, k = idx & 63;
        s_wo2t[n*72 + k] = ldbs<T>(A.Wo2, k*64 + n);
        s_wo1t[n*72 + k] = (k < 50) ? ldbs<T>(A.Wo1, (128+k)*64 + n) : (short)0;
    }
    // zero-pad rbfh k-range [50,68) once (each pass only rewrites k<50)
    {
        int k = lane;
        if (k >= 50){
            #pragma unroll
            for (int pp = 0; pp < 4; ++pp){ s_rbfh[w][pp][k] = 0.f; s_rbfh[w][pp][k+4 < 68 ? k+4 : 67] = 0.f; }
        }
    }

    float xi0 = ldv<T>(A.x, bi*3+0), xi1 = ldv<T>(A.x, bi*3+1), xi2 = ldv<T>(A.x, bi*3+2);

    // ---- s_x4 precompute: thread j computes xhat + d once ----
    {
        int j = tid;
        float dx = ldv<T>(A.x,(b*256+j)*3+0) - xi0;
        float dy = ldv<T>(A.x,(b*256+j)*3+1) - xi1;
        float dz = ldv<T>(A.x,(b*256+j)*3+2) - xi2;
        float dd = sqrtf(dx*dx + dy*dy + dz*dz + 1e-5f);
        float inv = 1.f/(dd + 1e-5f);
        s_x4[j][0] = dx*inv; s_x4[j][1] = dy*inv; s_x4[j][2] = dz*inv; s_x4[j][3] = dd;
    }

    int lane15 = lane & 15, quad = lane >> 4;

    // per-lane i-side constants
    float bo1v  = ldv<T>(A.bo1, lane);
    float wlast = ldv<T>(A.Wo1, 178*64 + lane);
    float u2v = 0.f;
    for (int f = 0; f < 64; ++f) u2v += s_hi[f] * ldv<T>(A.Wo1, (64+f)*64 + lane);
    if (w == 0){ s_u2[lane] = u2v; s_bo1[lane] = bo1v; s_wl[lane] = wlast; }
    float muv = 0.f, bev = 0.f, binv = 0.f, aiv = 0.f;
    if (lane < 50){
        muv = ldv<T>(A.means, lane); bev = ldv<T>(A.betas, lane); binv = ldv<T>(A.bin, lane);
        for (int f = 0; f < 64; ++f) aiv += s_hi[f] * ldv<T>(A.Win, (64+f)*50 + lane);
    }
    __syncthreads();   // all staged LDS + s_x4 + s_u2/s_bo1/s_wl visible

    float bo2c[4], u24[4], bo14[4], wl4[4];
    #pragma unroll
    for (int nf = 0; nf < 4; ++nf){
        bo2c[nf] = ldv<T>(A.bo2, nf*16 + lane15);
        u24[nf]  = s_u2[nf*16 + lane15];
        bo14[nf] = s_bo1[nf*16 + lane15];
        wl4[nf]  = s_wl[nf*16 + lane15];
    }

    // ================= edge phase: 16 passes x (4 waves x 4 pairs) =================
    for (int pass = 0; pass < 16; ++pass){
        int j0 = pass*16 + w*4;
        float dist[4];
        #pragma unroll
        for (int pp = 0; pp < 4; ++pp) dist[pp] = s_x4[j0+pp][3];

        if (lane < 50){
            #pragma unroll
            for (int pp = 0; pp < 4; ++pp){
                int j = j0 + pp;
                float h1 = Ajw[(b*256+j)*64 + lane] + aiv + binv;
                float dd = dist[pp];
                float cut = (dd < 5.f) ? 0.5f*(__cosf(dd*0.6283185307f) + 1.f) : 0.f;
                float ex = __expf(-dd) - muv;
                s_rbfh[w][pp][lane] = cut * __expf(-bev*ex*ex) * h1;
            }
        }

        // ---- o1 via MFMA: [4 pairs x 64k(rbfh, zero-pad)] @ Wo1r[64k x 64n] ----
        {
            bf16x8 ar[2];
            #pragma unroll
            for (int kk2 = 0; kk2 < 2; ++kk2){
                bf16x8 av = (bf16x8){0,0,0,0,0,0,0,0};
                if (lane15 < 4){
                    const float* rp = &s_rbfh[w][lane15][kk2*32 + quad*8];
                    f32x4 m0 = *(const f32x4*)rp;
                    f32x4 m1 = *(const f32x4*)(rp + 4);
                    av[0]=f2bs(m0[0]); av[1]=f2bs(m0[1]); av[2]=f2bs(m0[2]); av[3]=f2bs(m0[3]);
                    av[4]=f2bs(m1[0]); av[5]=f2bs(m1[1]); av[6]=f2bs(m1[2]); av[7]=f2bs(m1[3]);
                }
                ar[kk2] = av;
            }
            #pragma unroll
            for (int nf = 0; nf < 4; ++nf){
                int n = nf*16 + lane15;
                f32x4 Co1 = (f32x4){0.f,0.f,0.f,0.f};
                if (quad == 0){
                    #pragma unroll
                    for (int r = 0; r < 4; ++r)
                        Co1[r] = bs2f(U1w[(b*256 + j0 + r)*64 + n]) + u24[nf] + bo14[nf] + dist[r]*wl4[nf];
                }
                bf16x8 b0 = *(const bf16x8*)&s_wo1t[n*72 + quad*8];
                bf16x8 b1 = *(const bf16x8*)&s_wo1t[n*72 + 32 + quad*8];
                Co1 = __builtin_amdgcn_mfma_f32_16x16x32_bf16(ar[0], b0, Co1, 0, 0, 0);
                Co1 = __builtin_amdgcn_mfma_f32_16x16x32_bf16(ar[1], b1, Co1, 0, 0, 0);
                if (quad == 0){
                    s_mid[w][0][n] = siluf(Co1[0]);
                    s_mid[w][1][n] = siluf(Co1[1]);
                    s_mid[w][2][n] = siluf(Co1[2]);
                    s_mid[w][3][n] = siluf(Co1[3]);
                }
            }
        }

        // ---- o2 via MFMA: [4 pairs x 64k] @ Wo2[64k x 64n]; A rows 4..15 zero ----
        {
            bf16x8 av2[2];
            #pragma unroll
            for (int kk2 = 0; kk2 < 2; ++kk2){
                bf16x8 av = (bf16x8){0,0,0,0,0,0,0,0};
                if (lane15 < 4){
                    const float* mp = &s_mid[w][lane15][kk2*32 + quad*8];
                    f32x4 m0 = *(const f32x4*)mp;
                    f32x4 m1 = *(const f32x4*)(mp + 4);
                    av[0]=f2bs(m0[0]); av[1]=f2bs(m0[1]); av[2]=f2bs(m0[2]); av[3]=f2bs(m0[3]);
                    av[4]=f2bs(m1[0]); av[5]=f2bs(m1[1]); av[6]=f2bs(m1[2]); av[7]=f2bs(m1[3]);
                }
                av2[kk2] = av;
            }
            #pragma unroll
            for (int nf = 0; nf < 4; ++nf){
                int n = nf*16 + lane15;
                f32x4 Cc2 = (f32x4){bo2c[nf], bo2c[nf], bo2c[nf], bo2c[nf]};
                bf16x8 b0 = *(const bf16x8*)&s_wo2t[n*72 + quad*8];
                bf16x8 b1 = *(const bf16x8*)&s_wo2t[n*72 + 32 + quad*8];
                Cc2 = __builtin_amdgcn_mfma_f32_16x16x32_bf16(av2[0], b0, Cc2, 0, 0, 0);
                Cc2 = __builtin_amdgcn_mfma_f32_16x16x32_bf16(av2[1], b1, Cc2, 0, 0, 0);
                if (quad == 0){
                    s_e[j0+0][n] = __float2bfloat16(Cc2[0]);
                    s_e[j0+1][n] = __float2bfloat16(Cc2[1]);
                    s_e[j0+2][n] = __float2bfloat16(Cc2[2]);
                    s_e[j0+3][n] = __float2bfloat16(Cc2[3]);
                }
            }
        }
    }
    __syncthreads();   // single barrier: s_e now visible to all waves

    // ================= semantic attention logits (thread = j; b32 e-reads) =========
    {
        int j = tid;
        float a0 = ldv<T>(A.bsem,0), a1 = ldv<T>(A.bsem,1), a2 = ldv<T>(A.bsem,2), a3 = ldv<T>(A.bsem,3);
        const unsigned int* erow = (const unsigned int*)&s_e[j][0];   // j*33 dwords, aligned
        for (int f2 = 0; f2 < 32; ++f2){
            unsigned int u = erow[f2];
            float e0 = lo16f(u), e1 = hi16f(u);
            a0 += e0*bs2f(s_wsem[f2*8+0]) + e1*bs2f(s_wsem[f2*8+4]);
            a1 += e0*bs2f(s_wsem[f2*8+1]) + e1*bs2f(s_wsem[f2*8+5]);
            a2 += e0*bs2f(s_wsem[f2*8+2]) + e1*bs2f(s_wsem[f2*8+6]);
            a3 += e0*bs2f(s_wsem[f2*8+3]) + e1*bs2f(s_wsem[f2*8+7]);
        }
        a0 = celu2(a0); a1 = celu2(a1); a2 = celu2(a2); a3 = celu2(a3);
        if (j == i){ a0 -= 1e5f; a1 -= 1e5f; a2 -= 1e5f; a3 -= 1e5f; }
        s_att[j][0] = a0; s_att[j][1] = a1; s_att[j][2] = a2; s_att[j][3] = a3;
    }
    __syncthreads();

    // ================= softmax over j (4 heads) =================
    {
        float l0 = s_att[tid][0], l1 = s_att[tid][1], l2 = s_att[tid][2], l3 = s_att[tid][3];
        s_sm[tid*4+0]=l0; s_sm[tid*4+1]=l1; s_sm[tid*4+2]=l2; s_sm[tid*4+3]=l3;
        __syncthreads();
        for (int off = 128; off > 0; off >>= 1){
            if (tid < off){
                s_sm[tid*4+0] = fmaxf(s_sm[tid*4+0], s_sm[(tid+off)*4+0]);
                s_sm[tid*4+1] = fmaxf(s_sm[tid*4+1], s_sm[(tid+off)*4+1]);
                s_sm[tid*4+2] = fmaxf(s_sm[tid*4+2], s_sm[(tid+off)*4+2]);
                s_sm[tid*4+3] = fmaxf(s_sm[tid*4+3], s_sm[(tid+off)*4+3]);
            }
            __syncthreads();
        }
        float m0 = s_sm[0], m1 = s_sm[1], m2 = s_sm[2], m3 = s_sm[3];
        __syncthreads();
        float e0 = __expf(l0-m0), e1 = __expf(l1-m1), e2 = __expf(l2-m2), e3 = __expf(l3-m3);
        s_sm[tid*4+0]=e0; s_sm[tid*4+1]=e1; s_sm[tid*4+2]=e2; s_sm[tid*4+3]=e3;
        __syncthreads();
        for (int off = 128; off > 0; off >>= 1){
            if (tid < off){
                s_sm[tid*4+0] += s_sm[(tid+off)*4+0];
                s_sm[tid*4+1] += s_sm[(tid+off)*4+1];
                s_sm[tid*4+2] += s_sm[(tid+off)*4+2];
                s_sm[tid*4+3] += s_sm[(tid+off)*4+3];
            }
            __syncthreads();
        }
        s_att[tid][0] = e0 / s_sm[0];
        s_att[tid][1] = e1 / s_sm[1];
        s_att[tid][2] = e2 / s_sm[2];
        s_att[tid][3] = e3 / s_sm[3];
    }
    __syncthreads();

    // ================= h_e[c] = sum_j e[j][f]*att[j][h], c = 4f+h (R16 proven) ======
    {
        int f_he = tid >> 2, h_he = tid & 3;
        float he_acc = 0.f;
        for (int j2 = 0; j2 < 256; ++j2)
            he_acc += b2f(s_e[j2][f_he]) * s_att[j2][h_he];
        s_he[tid] = he_acc;
    }

    // ================= x-mixing via att-factored MFMA =================
    // P[j][n] = sum_h att[j][h] * (E @ WxH_h)[j][n]; wave w owns n in [w*64,w*64+64)
    {
        const short* se_s = (const short*)s_e;   // s_e[j][f], row stride 66 shorts
        float comb_acc[4][3];
        #pragma unroll
        for (int nf = 0; nf < 4; ++nf){ comb_acc[nf][0]=0.f; comb_acc[nf][1]=0.f; comb_acc[nf][2]=0.f; }

        #pragma unroll
        for (int nf = 0; nf < 4; ++nf){
            int n = w*64 + nf*16 + lane15;
            // hoist B for this n: Bh[h][ks] = WxH[h][n][ks*32+quad*8 .. +8]
            bf16x8 Bh[4][2];
            #pragma unroll
            for (int hh = 0; hh < 4; ++hh){
                const short* bp = wxt + (hh*256 + n)*64 + quad*8;
                Bh[hh][0] = *(const bf16x8*)(bp);
                Bh[hh][1] = *(const bf16x8*)(bp + 32);
            }

            for (int mt = 0; mt < 16; ++mt){
                int jq = mt*16 + quad*4;      // C/D row base for this lane
                // att rows for P-combine
                f32x4 att4[4];
                #pragma unroll
                for (int r = 0; r < 4; ++r) att4[r] = *(const f32x4*)&s_att[jq + r][0];
                // A-fragments direct from s_e: A[m=lane15][k=ks*32+quad*8+t]
                bf16x8 Af[2];
                #pragma unroll
                for (int ks = 0; ks < 2; ++ks){
                    const short* ep = se_s + (mt*16 + lane15)*66 + ks*32 + quad*8;
                    const unsigned int* ep32 = (const unsigned int*)ep;  // 4B-aligned (even offs)
                    unsigned int u0 = ep32[0], u1 = ep32[1], u2 = ep32[2], u3 = ep32[3];
                    bf16x8 av;
                    av[0]=(short)(u0 & 0xffff); av[1]=(short)(u0 >> 16);
                    av[2]=(short)(u1 & 0xffff); av[3]=(short)(u1 >> 16);
                    av[4]=(short)(u2 & 0xffff); av[5]=(short)(u2 >> 16);
                    av[6]=(short)(u3 & 0xffff); av[7]=(short)(u3 >> 16);
                    Af[ks] = av;
                }
                // P accumulation over heads
                float Pt[4] = {0.f, 0.f, 0.f, 0.f};   // [r]
                #pragma unroll
                for (int hh = 0; hh < 4; ++hh){
                    f32x4 Cc = (f32x4){0.f,0.f,0.f,0.f};
                    Cc = __builtin_amdgcn_mfma_f32_16x16x32_bf16(Af[0], Bh[hh][0], Cc, 0, 0, 0);
                    Cc = __builtin_amdgcn_mfma_f32_16x16x32_bf16(Af[1], Bh[hh][1], Cc, 0, 0, 0);
                    #pragma unroll
                    for (int r = 0; r < 4; ++r) Pt[r] += att4[r][hh] * Cc[r];
                }
                // epilogue: tanh + weighted xhat accumulation
                #pragma unroll
                for (int r = 0; r < 4; ++r){
                    int j = jq + r;
                    float cf = tanhfast(Pt[r]);
                    comb_acc[nf][0] += cf * s_x4[j][0];
                    comb_acc[nf][1] += cf * s_x4[j][1];
                    comb_acc[nf][2] += cf * s_x4[j][2];
                }
            }
        }

        // reduce over quads (j-coverage) and store: each wave owns 64 c's
        #pragma unroll
        for (int nf = 0; nf < 4; ++nf){
            #pragma unroll
            for (int d = 0; d < 3; ++d){
                float vsum = comb_acc[nf][d];
                vsum += __shfl_xor(vsum, 16);
                vsum += __shfl_xor(vsum, 32);
                if (quad == 0) s_red[(w*64 + nf*16 + lane15)*3 + d] = vsum;
            }
        }
    }
    __syncthreads();

    // ================= final per-node MLPs =================
    const float sc = 1.f/256.f;
    {
        float cb0 = s_red[tid*3+0]*sc, cb1 = s_red[tid*3+1]*sc, cb2 = s_red[tid*3+2]*sc;
        s_cn[tid] = cb0*cb0 + cb1*cb1 + cb2*cb2;
    }
    __syncthreads();

    if (tid < 64){
        int f = tid;
        float acc = ldv<T>(A.bp1, f);
        for (int c = 0; c < 256; ++c) acc += s_cn[c] * ldv<T>(A.Wp1, c*64 + f);
        s_f1[f] = siluf(acc);
    }
    __syncthreads();
    if (tid < 64){
        int f = tid;
        float acc = ldv<T>(A.bp2, f);
        for (int k = 0; k < 64; ++k) acc += s_f1[k] * ldv<T>(A.Wp2, k*64 + f);
        s_f2[f] = siluf(acc);
    }
    __syncthreads();
    if (tid < 64){
        int f = tid;
        float acc = ldv<T>(A.bn1, f);
        for (int r = 0; r < 64; ++r)  acc += s_hi[r] * ldv<T>(A.Wn1, r*64 + f);
        for (int r = 0; r < 256; ++r) acc += s_he[r] * ldv<T>(A.Wn1, (64+r)*64 + f);
        for (int r = 0; r < 64; ++r)  acc += s_f2[r] * ldv<T>(A.Wn1, (320+r)*64 + f);
        s_f3[f] = siluf(acc);
    }
    __syncthreads();
    if (tid < 64){
        int f = tid;
        float acc = ldv<T>(A.bn2, f);
        for (int k = 0; k < 64; ++k) acc += s_f3[k] * ldv<T>(A.Wn2, k*64 + f);
        float hn = s_hi[f] + siluf(acc);
        stv<T>(out, bi*64 + f, hn);
        s_f4[f] = hn;
    }
    __syncthreads();
    if (tid < 64){
        int f = tid;
        float acc = ldv<T>(A.bv1, f);
        for (int k = 0; k < 64; ++k) acc += s_f4[k] * ldv<T>(A.Wv1, k*64 + f);
        float term = siluf(acc) * ldv<T>(A.Wv2, f);
        #pragma unroll
        for (int off = 32; off > 0; off >>= 1) term += __shfl_down(term, off);
        float vscale = 2.f / (1.f + __expf(-__shfl(term, 0)));

        float dv0 = 0.f, dv1 = 0.f, dv2 = 0.f;
        #pragma unroll
        for (int q = 0; q < 4; ++q){
            int c = q*64 + f;
            float wv = ldv<T>(A.Wvm, c);
            dv0 += s_red[c*3+0]*sc*wv;
            dv1 += s_red[c*3+1]*sc*wv;
            dv2 += s_red[c*3+2]*sc*wv;
        }
        #pragma unroll
        for (int off = 32; off > 0; off >>= 1){
            dv0 += __shfl_down(dv0, off);
            dv1 += __shfl_down(dv1, off);
            dv2 += __shfl_down(dv2, off);
        }
        dv0 = __shfl(dv0, 0); dv1 = __shfl(dv1, 0); dv2 = __shfl(dv2, 0);
        if (f < 3){
            float dvl = (f == 0) ? dv0 : (f == 1 ? dv1 : dv2);
            float vn = dvl + vscale * ldv<T>(A.v, bi*3 + f);
            float xn = ldv<T>(A.x, bi*3 + f) + vn;
            stv<T>(out, 32768 + bi*3 + f, xn);  // x_new
            stv<T>(out, 34304 + bi*3 + f, vn);  // v_new
        }
    }
}

extern "C" void kernel_launch(void* const* d_in, const int* in_sizes, int n_in,
                              void* d_out, int out_size, void* d_ws, size_t ws_size,
                              hipStream_t stream)
{
    Args A;
    A.h     = d_in[0];  A.x     = d_in[1];  A.v     = d_in[2];
    A.Win   = d_in[3];  A.bin   = d_in[4];  A.means = d_in[5];  A.betas = d_in[6];
    A.Wo1   = d_in[7];  A.bo1   = d_in[8];  A.Wo2   = d_in[9];  A.bo2   = d_in[10];
    A.Wsem  = d_in[11]; A.bsem  = d_in[12]; A.Wx    = d_in[13];
    A.Wp1   = d_in[14]; A.bp1   = d_in[15]; A.Wp2   = d_in[16]; A.bp2   = d_in[17];
    A.Wn1   = d_in[18]; A.bn1   = d_in[19]; A.Wn2   = d_in[20]; A.bn2   = d_in[21];
    A.Wv1   = d_in[22]; A.bv1   = d_in[23]; A.Wv2   = d_in[24]; A.Wvm   = d_in[25];

    // ws layout: flag 64B | U1 bf16 512x64 (64KB) | Aj f32 512x64 (128KB) | WxH bf16 4x256x64 (128KB)
    int*   flag = (int*)d_ws;
    short* U1b  = (short*)((char*)d_ws + 64);
    float* Aj   = (float*)((char*)d_ws + 64 + 65536);
    short* WxT  = (short*)((char*)d_ws + 64 + 65536 + 131072);

    k_detect<<<1, 64, 0, stream>>>(A.means, flag);
    k_nodepre<bf16,  0><<<NNODE, 64, 0, stream>>>(A, flag, U1b, Aj, WxT);
    k_nodepre<float, 1><<<NNODE, 64, 0, stream>>>(A, flag, U1b, Aj, WxT);
    k_sake<bf16,  0><<<NNODE, 256, 0, stream>>>(A, flag, U1b, Aj, WxT, d_out);
    k_sake<float, 1><<<NNODE, 256, 0, stream>>>(A, flag, U1b, Aj, WxT, d_out);
}